// Round 11
// baseline (151.636 us; speedup 1.0000x reference)
//
#include <hip/hip_runtime.h>

#define N_PATHS 300000
#define REALBZ  1024
#define D       32
#define RED_BLOCKS 64

typedef __attribute__((ext_vector_type(8))) short  short8;   // 8 bf16 = 4 VGPR (MFMA A/B)
typedef __attribute__((ext_vector_type(4))) float  f32x4;    // MFMA C/D
typedef __attribute__((ext_vector_type(4))) unsigned int uint4v;

#define LOG2E 1.44269504088896340736f

__device__ __forceinline__ float fsig(float x) {
    float e = __builtin_amdgcn_exp2f(-LOG2E * x);
    return __builtin_amdgcn_rcpf(1.f + e);
}
__device__ __forceinline__ float ftanh(float x) {
    float e = __builtin_amdgcn_exp2f(-2.f * LOG2E * x);
    return fmaf(2.f, __builtin_amdgcn_rcpf(1.f + e), -1.f);
}
__device__ __forceinline__ unsigned short bf16_rne(float f) {
    unsigned u = __float_as_uint(f);
    u += 0x7FFF + ((u >> 16) & 1);
    return (unsigned short)(u >> 16);
}
__device__ __forceinline__ float bf16_to_f(unsigned short s) {
    return __uint_as_float(((unsigned)s) << 16);
}
__device__ __forceinline__ unsigned pack2(float a, float b) {
    return (unsigned)bf16_rne(a) | ((unsigned)bf16_rne(b) << 16);
}

// ---------------- single prep dispatch ----------------
__global__ void prep_kernel(const int* __restrict__ path,
                            const float* __restrict__ all_emb,
                            const float* __restrict__ edge_emb,
                            const float* __restrict__ w_ih,
                            const float* __restrict__ w_hh,
                            const float* __restrict__ b_ih,
                            const float* __restrict__ b_hh,
                            unsigned short* __restrict__ embt,
                            unsigned short* __restrict__ Wihb,
                            unsigned short* __restrict__ Whhb,
                            unsigned short* __restrict__ h2b,
                            unsigned* __restrict__ pk,
                            float* __restrict__ score,
                            int do_pack)
{
    const int b = blockIdx.x, tid = threadIdx.x;
    if (b < 512) {
        __shared__ float gsh[96];
        __shared__ float h1[32];
        const int v0 = b >> 3;
        if (tid < 96) {                       // stage 1a: gate-parallel matvec
            const int j = tid & 31, g = tid >> 5;
            const float* x = all_emb + v0 * D;
            float acc = b_ih[g * 32 + j];
#pragma unroll
            for (int k = 0; k < D; ++k)
                acc = fmaf(w_ih[(g * 32 + j) * D + k], x[k], acc);
            gsh[tid] = acc;
        }
        __syncthreads();
        if (tid < 32) {                       // stage 1b: nonlinearity, h=0
            int j = tid;
            float r = fsig(gsh[j] + b_hh[j]);
            float z = fsig(gsh[32 + j] + b_hh[32 + j]);
            float n = ftanh(fmaf(r, b_hh[64 + j], gsh[64 + j]));
            h1[j] = (1.f - z) * n;
        }
        __syncthreads();
        const int v1 = (b & 7) * 8 + (tid >> 5);   // stage 2: 8 v1 x 32 j
        const int j  = tid & 31;
        const float* x = edge_emb + v1 * D;
        float gr = b_ih[j], gz = b_ih[32 + j], gn = b_ih[64 + j];
        float dr = b_hh[j], dz = b_hh[32 + j], dn = b_hh[64 + j];
#pragma unroll
        for (int k = 0; k < D; ++k) {
            float xk = x[k], hk = h1[k];
            gr = fmaf(w_ih[j * D + k],        xk, gr);
            gz = fmaf(w_ih[(32 + j) * D + k], xk, gz);
            gn = fmaf(w_ih[(64 + j) * D + k], xk, gn);
            dr = fmaf(w_hh[j * D + k],        hk, dr);
            dz = fmaf(w_hh[(32 + j) * D + k], hk, dz);
            dn = fmaf(w_hh[(64 + j) * D + k], hk, dn);
        }
        float r = fsig(gr + dr);
        float z = fsig(gz + dz);
        float n = ftanh(fmaf(r, dn, gn));
        h2b[(v0 * 64 + v1) * D + j] = bf16_rne(fmaf(z, h1[j] - n, n));
    } else if (b < 556) {
        int t = (b - 512) * 256 + tid;
        if (t < 2048)        embt[t] = bf16_rne(all_emb[t]);
        else if (t < 4096)   embt[t] = bf16_rne(edge_emb[t - 2048]);
        else if (t < 7168)   Wihb[t - 4096] = bf16_rne(w_ih[t - 4096]);
        else if (t < 10240)  Whhb[t - 7168] = bf16_rne(w_hh[t - 7168]);
        else if (t < 10240 + REALBZ) score[t - 10240] = 0.f;   // reduce adds into this
    } else if (do_pack) {
        int t = (b - 556) * 256 + tid;
        if (t < N_PATHS) {
            const int* r = path + t * 5;
            pk[t] = (unsigned)r[0] | ((unsigned)r[1] << 6) | ((unsigned)r[2] << 12)
                  | ((unsigned)r[3] << 18) | ((unsigned)r[4] << 24);
        }
    }
}

// ---------------- main: gates^T MFMA, bpermute transpose, ROLLED l-loop ----------------
// I$ theory (R11): the fully-unrolled 3-step body is ~25-30KB ~ the 32KB I$;
// all pipes idle (VALU 22%, MFMA 4%, mem tiny) = front-end starvation.
// Rolled l-loop shrinks code ~3x. Path word kept packed in a register; step
// value extracted with a dynamic shift (no private-array scratch indexing).
template <int USE_PK, int STORE>
__global__ __launch_bounds__(256) void gru_mfma_kernel(
    const int* __restrict__ path,
    const unsigned* __restrict__ pk,
    const int* __restrict__ path_idx,
    const unsigned short* __restrict__ embt,
    const unsigned short* __restrict__ Wihb,
    const unsigned short* __restrict__ Whhb,
    const unsigned short* __restrict__ h2b,
    const float* __restrict__ b_ih,
    const float* __restrict__ b_hh,
    const float* __restrict__ w_lin,
    const float* __restrict__ b_lin,
    float* __restrict__ psc,
    float* __restrict__ score)
{
    const int lane = threadIdx.x & 63;
    const int lc   = lane & 15;
    const int quad = lane >> 4;
    const int wu   = blockIdx.x * 4 + (threadIdx.x >> 6);   // wave unit
    const int pbase = wu * 32;

    short8 Aih[6], Ahh[6];
#pragma unroll
    for (int jt = 0; jt < 6; ++jt) {
        Aih[jt] = *(const short8*)(Wihb + (jt * 16 + lc) * D + quad * 8);
        Ahh[jt] = *(const short8*)(Whhb + (jt * 16 + lc) * D + quad * 8);
    }
    f32x4 brz[4], bxn[2], bhn[2];
#pragma unroll
    for (int jt = 0; jt < 4; ++jt)
#pragma unroll
        for (int q = 0; q < 4; ++q)
            brz[jt][q] = b_ih[jt * 16 + quad * 4 + q] + b_hh[jt * 16 + quad * 4 + q];
#pragma unroll
    for (int jh = 0; jh < 2; ++jh)
#pragma unroll
        for (int q = 0; q < 4; ++q) {
            bxn[jh][q] = b_ih[64 + jh * 16 + quad * 4 + q];
            bhn[jh][q] = b_hh[64 + jh * 16 + quad * 4 + q];
        }

    unsigned wreg[2];
    short8 Bh[2];
    float hold[2][2][4];
#pragma unroll
    for (int nt = 0; nt < 2; ++nt) {
        int p = min(pbase + nt * 16 + lc, N_PATHS - 1);
        if (USE_PK) {
            wreg[nt] = pk[p];
        } else {
            const int* r = path + p * 5;
            wreg[nt] = (unsigned)r[0] | ((unsigned)r[1] << 6) | ((unsigned)r[2] << 12)
                     | ((unsigned)r[3] << 18) | ((unsigned)r[4] << 24);
        }
        int v0 = wreg[nt] & 63, v1 = (wreg[nt] >> 6) & 63;
        const unsigned short* hsrc = h2b + (v0 * 64 + v1) * D;
        Bh[nt] = *(const short8*)(hsrc + quad * 8);
#pragma unroll
        for (int jh = 0; jh < 2; ++jh) {
            const unsigned short* c = hsrc + jh * 16 + quad * 4;
#pragma unroll
            for (int q = 0; q < 4; ++q) hold[nt][jh][q] = bf16_to_f(c[q]);
        }
    }

    const int qlo = 2 * (quad & 1) + (quad >> 1);
    const int a_lo = 4 * (lc + 16 * qlo);
    const int a_hi = 4 * (lc + 16 * (qlo ^ 1));
    const bool hi = quad >= 2;
    const bool oddq = (quad & 1) != 0;

#pragma unroll 1
    for (int l = 2; l < 5; ++l) {
        const int sh  = 6 * l;
        const int par = l & 1;
        short8 Bx[2];
#pragma unroll
        for (int nt = 0; nt < 2; ++nt) {
            int v = (wreg[nt] >> sh) & 63;
            Bx[nt] = *(const short8*)(embt + (par * 64 + v) * D + quad * 8);
        }

#pragma unroll
        for (int nt = 0; nt < 2; ++nt) {
            f32x4 rz[4], xn[2], hn[2];
#pragma unroll
            for (int jt = 0; jt < 4; ++jt) {
                f32x4 acc = brz[jt];
                acc = __builtin_amdgcn_mfma_f32_16x16x32_bf16(Aih[jt], Bx[nt], acc, 0, 0, 0);
                acc = __builtin_amdgcn_mfma_f32_16x16x32_bf16(Ahh[jt], Bh[nt], acc, 0, 0, 0);
                rz[jt] = acc;
            }
#pragma unroll
            for (int jh = 0; jh < 2; ++jh) {
                xn[jh] = __builtin_amdgcn_mfma_f32_16x16x32_bf16(Aih[4 + jh], Bx[nt], bxn[jh], 0, 0, 0);
                hn[jh] = __builtin_amdgcn_mfma_f32_16x16x32_bf16(Ahh[4 + jh], Bh[nt], bhn[jh], 0, 0, 0);
            }
            unsigned R[2][2];
#pragma unroll
            for (int jh = 0; jh < 2; ++jh) {
                float hv[4];
#pragma unroll
                for (int q = 0; q < 4; ++q) {
                    float r = fsig(rz[jh][q]);
                    float z = fsig(rz[2 + jh][q]);
                    float n = ftanh(fmaf(r, hn[jh][q], xn[jh][q]));
                    hv[q] = fmaf(z, hold[nt][jh][q] - n, n);
                    hold[nt][jh][q] = hv[q];
                }
                R[jh][0] = pack2(hv[0], hv[1]);
                R[jh][1] = pack2(hv[2], hv[3]);
            }
            if (l != 4) {   // wave-uniform branch; skip transform after last step
                unsigned v0c = oddq ? R[1][0] : R[0][0];
                unsigned v1c = oddq ? R[1][1] : R[0][1];
                unsigned v2c = oddq ? R[0][0] : R[1][0];
                unsigned v3c = oddq ? R[0][1] : R[1][1];
                unsigned r0 = (unsigned)__builtin_amdgcn_ds_bpermute(a_lo, (int)v0c);
                unsigned r1 = (unsigned)__builtin_amdgcn_ds_bpermute(a_lo, (int)v1c);
                unsigned r2 = (unsigned)__builtin_amdgcn_ds_bpermute(a_hi, (int)v2c);
                unsigned r3 = (unsigned)__builtin_amdgcn_ds_bpermute(a_hi, (int)v3c);
                uint4v t;
                t.x = hi ? r2 : r0;
                t.y = hi ? r3 : r1;
                t.z = hi ? r0 : r2;
                t.w = hi ? r1 : r3;
                Bh[nt] = __builtin_bit_cast(short8, t);
            }
        }
    }

    // epilogue: dot(w_lin, h), quad-reduce; STORE: coalesced per-path store
    float4 wl0 = *(const float4*)(w_lin + quad * 4);
    float4 wl1 = *(const float4*)(w_lin + 16 + quad * 4);
    float s[2];
#pragma unroll
    for (int nt = 0; nt < 2; ++nt) {
        float t = 0.f;
        t = fmaf(wl0.x, hold[nt][0][0], t); t = fmaf(wl0.y, hold[nt][0][1], t);
        t = fmaf(wl0.z, hold[nt][0][2], t); t = fmaf(wl0.w, hold[nt][0][3], t);
        t = fmaf(wl1.x, hold[nt][1][0], t); t = fmaf(wl1.y, hold[nt][1][1], t);
        t = fmaf(wl1.z, hold[nt][1][2], t); t = fmaf(wl1.w, hold[nt][1][3], t);
        t += __shfl_xor(t, 16, 64);
        t += __shfl_xor(t, 32, 64);
        s[nt] = t;
    }
    if (quad < 2) {
        int p = pbase + quad * 16 + lc;
        if (p < N_PATHS) {
            float val = (quad ? s[1] : s[0]) + b_lin[0];
            if (STORE) psc[p] = val;
            else       atomicAdd(&score[path_idx[p]], val);
        }
    }
}

// ---------------- segment-sum: 64 blocks, LDS bins, 1 global atomic/bin/block ----------------
__global__ __launch_bounds__(1024) void reduce_kernel(const float* __restrict__ psc,
                                                      const int* __restrict__ path_idx,
                                                      float* __restrict__ out)
{
    __shared__ float bins[REALBZ];
    const int tid = threadIdx.x;
    bins[tid] = 0.f;
    __syncthreads();
    const int4*   pi4 = (const int4*)path_idx;
    const float4* ps4 = (const float4*)psc;
#pragma unroll 1
    for (int i = blockIdx.x * 1024 + tid; i < N_PATHS / 4; i += RED_BLOCKS * 1024) {
        int4   idx = pi4[i];
        float4 v   = ps4[i];
        atomicAdd(&bins[idx.x], v.x);
        atomicAdd(&bins[idx.y], v.y);
        atomicAdd(&bins[idx.z], v.z);
        atomicAdd(&bins[idx.w], v.w);
    }
    __syncthreads();
    atomicAdd(&out[tid], bins[tid]);
}

extern "C" void kernel_launch(void* const* d_in, const int* in_sizes, int n_in,
                              void* d_out, int out_size, void* d_ws, size_t ws_size,
                              hipStream_t stream)
{
    // 0 users 1 path 2 path_idx 3 all_emb 4 edge_emb 5 virtual_emb(unused)
    // 6 w_ih 7 w_hh 8 b_ih 9 b_hh 10 w_lin 11 b_lin
    const int*   path     = (const int*)  d_in[1];
    const int*   path_idx = (const int*)  d_in[2];
    const float* all_emb  = (const float*)d_in[3];
    const float* edge_emb = (const float*)d_in[4];
    const float* w_ih     = (const float*)d_in[6];
    const float* w_hh     = (const float*)d_in[7];
    const float* b_ih     = (const float*)d_in[8];
    const float* b_hh     = (const float*)d_in[9];
    const float* w_lin    = (const float*)d_in[10];
    const float* b_lin    = (const float*)d_in[11];

    // ws (bytes): embt @0 (8K) | Wihb @8192 (6K) | Whhb @14336 (6K)
    //             | h2b @20480 (256K) | pk @282624 (1.2M) | psc @1482624 (1.2M)
    char* ws = (char*)d_ws;
    unsigned short* embt = (unsigned short*)ws;
    unsigned short* Wihb = (unsigned short*)(ws + 8192);
    unsigned short* Whhb = (unsigned short*)(ws + 14336);
    unsigned short* h2b  = (unsigned short*)(ws + 20480);
    unsigned*       pk   = (unsigned*)(ws + 282624);
    float*          psc  = (float*)(ws + 1482624);
    const size_t need_pk  = 282624 + (size_t)N_PATHS * 4;
    const size_t need_psc = 1482624 + (size_t)N_PATHS * 4;
    const int use_pk  = (ws_size >= need_pk) ? 1 : 0;
    const int use_psc = (ws_size >= need_psc) ? 1 : 0;

    float* score = (float*)d_out;

    const int pack_blocks = use_pk ? (N_PATHS + 255) / 256 : 0;
    prep_kernel<<<556 + pack_blocks, 256, 0, stream>>>(
        path, all_emb, edge_emb, w_ih, w_hh, b_ih, b_hh,
        embt, Wihb, Whhb, h2b, pk, score, use_pk);

    const int grid = (N_PATHS / 32 + 3) / 4;   // 9375 wave units, 4 waves/block
    if (use_pk && use_psc) {
        gru_mfma_kernel<1, 1><<<grid, 256, 0, stream>>>(
            path, pk, path_idx, embt, Wihb, Whhb, h2b, b_ih, b_hh, w_lin, b_lin, psc, score);
        reduce_kernel<<<RED_BLOCKS, 1024, 0, stream>>>(psc, path_idx, score);
    } else if (use_pk) {
        gru_mfma_kernel<1, 0><<<grid, 256, 0, stream>>>(
            path, pk, path_idx, embt, Wihb, Whhb, h2b, b_ih, b_hh, w_lin, b_lin, psc, score);
    } else {
        gru_mfma_kernel<0, 0><<<grid, 256, 0, stream>>>(
            path, pk, path_idx, embt, Wihb, Whhb, h2b, b_ih, b_hh, w_lin, b_lin, psc, score);
    }
}

// Round 14
// 138.404 us; speedup vs baseline: 1.0956x; 1.0956x over previous
//
#include <hip/hip_runtime.h>

#define N_PATHS 300000
#define REALBZ  1024
#define D       32
#define RED_BLOCKS 64
#define N_UNITS    9375            /* 300000/32 wave-units */
#define MAIN_GRID  2344            /* ceil(9375/4) 256-thr blocks, 1 unit/wave */

typedef __attribute__((ext_vector_type(8))) short  short8;   // 8 bf16 = 4 VGPR (MFMA A/B)
typedef __attribute__((ext_vector_type(4))) float  f32x4;    // MFMA C/D
typedef __attribute__((ext_vector_type(4))) unsigned int uint4v;

#define LOG2E 1.44269504088896340736f

__device__ __forceinline__ float fsig(float x) {
    float e = __builtin_amdgcn_exp2f(-LOG2E * x);
    return __builtin_amdgcn_rcpf(1.f + e);
}
__device__ __forceinline__ float ftanh(float x) {
    float e = __builtin_amdgcn_exp2f(-2.f * LOG2E * x);
    return fmaf(2.f, __builtin_amdgcn_rcpf(1.f + e), -1.f);
}
__device__ __forceinline__ unsigned short bf16_rne(float f) {
    unsigned u = __float_as_uint(f);
    u += 0x7FFF + ((u >> 16) & 1);
    return (unsigned short)(u >> 16);
}
__device__ __forceinline__ float bf16_to_f(unsigned short s) {
    return __uint_as_float(((unsigned)s) << 16);
}
__device__ __forceinline__ unsigned pack2(float a, float b) {
    return (unsigned)bf16_rne(a) | ((unsigned)bf16_rne(b) << 16);
}

// ---------------- single prep dispatch ----------------
__global__ void prep_kernel(const int* __restrict__ path,
                            const float* __restrict__ all_emb,
                            const float* __restrict__ edge_emb,
                            const float* __restrict__ w_ih,
                            const float* __restrict__ w_hh,
                            const float* __restrict__ b_ih,
                            const float* __restrict__ b_hh,
                            unsigned short* __restrict__ embt,
                            unsigned short* __restrict__ Wihb,
                            unsigned short* __restrict__ Whhb,
                            unsigned short* __restrict__ h2b,
                            unsigned* __restrict__ pk,
                            float* __restrict__ score,
                            int do_pack)
{
    const int b = blockIdx.x, tid = threadIdx.x;
    if (b < 512) {
        __shared__ float gsh[96];
        __shared__ float h1[32];
        const int v0 = b >> 3;
        if (tid < 96) {                       // stage 1a: gate-parallel matvec
            const int j = tid & 31, g = tid >> 5;
            const float* x = all_emb + v0 * D;
            float acc = b_ih[g * 32 + j];
#pragma unroll
            for (int k = 0; k < D; ++k)
                acc = fmaf(w_ih[(g * 32 + j) * D + k], x[k], acc);
            gsh[tid] = acc;
        }
        __syncthreads();
        if (tid < 32) {                       // stage 1b: nonlinearity, h=0
            int j = tid;
            float r = fsig(gsh[j] + b_hh[j]);
            float z = fsig(gsh[32 + j] + b_hh[32 + j]);
            float n = ftanh(fmaf(r, b_hh[64 + j], gsh[64 + j]));
            h1[j] = (1.f - z) * n;
        }
        __syncthreads();
        const int v1 = (b & 7) * 8 + (tid >> 5);   // stage 2: 8 v1 x 32 j
        const int j  = tid & 31;
        const float* x = edge_emb + v1 * D;
        float gr = b_ih[j], gz = b_ih[32 + j], gn = b_ih[64 + j];
        float dr = b_hh[j], dz = b_hh[32 + j], dn = b_hh[64 + j];
#pragma unroll
        for (int k = 0; k < D; ++k) {
            float xk = x[k], hk = h1[k];
            gr = fmaf(w_ih[j * D + k],        xk, gr);
            gz = fmaf(w_ih[(32 + j) * D + k], xk, gz);
            gn = fmaf(w_ih[(64 + j) * D + k], xk, gn);
            dr = fmaf(w_hh[j * D + k],        hk, dr);
            dz = fmaf(w_hh[(32 + j) * D + k], hk, dz);
            dn = fmaf(w_hh[(64 + j) * D + k], hk, dn);
        }
        float r = fsig(gr + dr);
        float z = fsig(gz + dz);
        float n = ftanh(fmaf(r, dn, gn));
        h2b[(v0 * 64 + v1) * D + j] = bf16_rne(fmaf(z, h1[j] - n, n));
    } else if (b < 556) {
        int t = (b - 512) * 256 + tid;
        if (t < 2048)        embt[t] = bf16_rne(all_emb[t]);
        else if (t < 4096)   embt[t] = bf16_rne(edge_emb[t - 2048]);
        else if (t < 7168)   Wihb[t - 4096] = bf16_rne(w_ih[t - 4096]);
        else if (t < 10240)  Whhb[t - 7168] = bf16_rne(w_hh[t - 7168]);
        else if (t < 10240 + REALBZ) score[t - 10240] = 0.f;   // reduce adds into this
    } else if (do_pack) {
        int t = (b - 556) * 256 + tid;
        if (t < N_PATHS) {
            const int* r = path + t * 5;
            pk[t] = (unsigned)r[0] | ((unsigned)r[1] << 6) | ((unsigned)r[2] << 12)
                  | ((unsigned)r[3] << 18) | ((unsigned)r[4] << 24);
        }
    }
}

// ---------------- main: gates^T MFMA, bpermute transpose, rolled l-loop ----------------
// R14: ILP-focused. launch_bounds(256,2) lets the allocator use up to 256 VGPR
// (R11's 88-VGPR compile serialized the 16 independent gate chains — occupancy
// was never the limit: total work is only ~9 waves/SIMD deep). embt staged in
// LDS (8KB): per-step Bx gathers at ds_read latency instead of L2. 1 unit/wave.
// Handoff to reduce stays at the DISPATCH BOUNDARY (R12/R13 intra-dispatch
// handoff failed per-XCD coherence even with agent-scope atomics — do not retry).
template <int USE_PK, int STORE>
__global__ __launch_bounds__(256, 2) void gru_mfma_kernel(
    const int* __restrict__ path,
    const unsigned* __restrict__ pk,
    const int* __restrict__ path_idx,
    const unsigned short* __restrict__ embt,
    const unsigned short* __restrict__ Wihb,
    const unsigned short* __restrict__ Whhb,
    const unsigned short* __restrict__ h2b,
    const float* __restrict__ b_ih,
    const float* __restrict__ b_hh,
    const float* __restrict__ w_lin,
    const float* __restrict__ b_lin,
    float* __restrict__ psc,
    float* __restrict__ score)
{
    __shared__ unsigned short esh[4096];       // embt copy [par*64+v][32], 8 KB
    {
        const uint4v* src = (const uint4v*)embt;
        uint4v* dst = (uint4v*)esh;
        dst[threadIdx.x]       = src[threadIdx.x];
        dst[threadIdx.x + 256] = src[threadIdx.x + 256];
    }
    __syncthreads();

    const int lane = threadIdx.x & 63;
    const int lc   = lane & 15;
    const int quad = lane >> 4;
    const int wu   = blockIdx.x * 4 + (threadIdx.x >> 6);   // wave unit, 1 unit/wave
    if (wu >= N_UNITS) return;                 // wave-uniform; no barriers below
    const int pbase = wu * 32;

    short8 Aih[6], Ahh[6];
#pragma unroll
    for (int jt = 0; jt < 6; ++jt) {
        Aih[jt] = *(const short8*)(Wihb + (jt * 16 + lc) * D + quad * 8);
        Ahh[jt] = *(const short8*)(Whhb + (jt * 16 + lc) * D + quad * 8);
    }
    f32x4 brz[4], bxn[2], bhn[2];
#pragma unroll
    for (int jt = 0; jt < 4; ++jt)
#pragma unroll
        for (int q = 0; q < 4; ++q)
            brz[jt][q] = b_ih[jt * 16 + quad * 4 + q] + b_hh[jt * 16 + quad * 4 + q];
#pragma unroll
    for (int jh = 0; jh < 2; ++jh)
#pragma unroll
        for (int q = 0; q < 4; ++q) {
            bxn[jh][q] = b_ih[64 + jh * 16 + quad * 4 + q];
            bhn[jh][q] = b_hh[64 + jh * 16 + quad * 4 + q];
        }

    unsigned wreg[2];
    short8 Bh[2];
    float hold[2][2][4];
#pragma unroll
    for (int nt = 0; nt < 2; ++nt) {
        int p = pbase + nt * 16 + lc;          // 9375*32 == N_PATHS exactly
        if (USE_PK) {
            wreg[nt] = pk[p];
        } else {
            const int* r = path + p * 5;
            wreg[nt] = (unsigned)r[0] | ((unsigned)r[1] << 6) | ((unsigned)r[2] << 12)
                     | ((unsigned)r[3] << 18) | ((unsigned)r[4] << 24);
        }
        int v0 = wreg[nt] & 63, v1 = (wreg[nt] >> 6) & 63;
        const unsigned short* hsrc = h2b + (v0 * 64 + v1) * D;
        Bh[nt] = *(const short8*)(hsrc + quad * 8);
#pragma unroll
        for (int jh = 0; jh < 2; ++jh) {
            const unsigned short* c = hsrc + jh * 16 + quad * 4;
#pragma unroll
            for (int q = 0; q < 4; ++q) hold[nt][jh][q] = bf16_to_f(c[q]);
        }
    }

    const int qlo = 2 * (quad & 1) + (quad >> 1);
    const int a_lo = 4 * (lc + 16 * qlo);
    const int a_hi = 4 * (lc + 16 * (qlo ^ 1));
    const bool hi = quad >= 2;
    const bool oddq = (quad & 1) != 0;

#pragma unroll 1
    for (int l = 2; l < 5; ++l) {
        const int sh  = 6 * l;
        const int par = l & 1;
        short8 Bx[2];
#pragma unroll
        for (int nt = 0; nt < 2; ++nt) {
            int v = (wreg[nt] >> sh) & 63;
            Bx[nt] = *(const short8*)(esh + (par * 64 + v) * D + quad * 8);   // LDS
        }

#pragma unroll
        for (int nt = 0; nt < 2; ++nt) {
            f32x4 rz[4], xn[2], hn[2];
#pragma unroll
            for (int jt = 0; jt < 4; ++jt) {
                f32x4 acc = brz[jt];
                acc = __builtin_amdgcn_mfma_f32_16x16x32_bf16(Aih[jt], Bx[nt], acc, 0, 0, 0);
                acc = __builtin_amdgcn_mfma_f32_16x16x32_bf16(Ahh[jt], Bh[nt], acc, 0, 0, 0);
                rz[jt] = acc;
            }
#pragma unroll
            for (int jh = 0; jh < 2; ++jh) {
                xn[jh] = __builtin_amdgcn_mfma_f32_16x16x32_bf16(Aih[4 + jh], Bx[nt], bxn[jh], 0, 0, 0);
                hn[jh] = __builtin_amdgcn_mfma_f32_16x16x32_bf16(Ahh[4 + jh], Bh[nt], bhn[jh], 0, 0, 0);
            }
            unsigned R[2][2];
#pragma unroll
            for (int jh = 0; jh < 2; ++jh) {
                float hv[4];
#pragma unroll
                for (int q = 0; q < 4; ++q) {
                    float r = fsig(rz[jh][q]);
                    float z = fsig(rz[2 + jh][q]);
                    float n = ftanh(fmaf(r, hn[jh][q], xn[jh][q]));
                    hv[q] = fmaf(z, hold[nt][jh][q] - n, n);
                    hold[nt][jh][q] = hv[q];
                }
                R[jh][0] = pack2(hv[0], hv[1]);
                R[jh][1] = pack2(hv[2], hv[3]);
            }
            if (l != 4) {   // wave-uniform; skip transform after last step
                unsigned v0c = oddq ? R[1][0] : R[0][0];
                unsigned v1c = oddq ? R[1][1] : R[0][1];
                unsigned v2c = oddq ? R[0][0] : R[1][0];
                unsigned v3c = oddq ? R[0][1] : R[1][1];
                unsigned r0 = (unsigned)__builtin_amdgcn_ds_bpermute(a_lo, (int)v0c);
                unsigned r1 = (unsigned)__builtin_amdgcn_ds_bpermute(a_lo, (int)v1c);
                unsigned r2 = (unsigned)__builtin_amdgcn_ds_bpermute(a_hi, (int)v2c);
                unsigned r3 = (unsigned)__builtin_amdgcn_ds_bpermute(a_hi, (int)v3c);
                uint4v t;
                t.x = hi ? r2 : r0;
                t.y = hi ? r3 : r1;
                t.z = hi ? r0 : r2;
                t.w = hi ? r1 : r3;
                Bh[nt] = __builtin_bit_cast(short8, t);
            }
        }
    }

    // epilogue: dot(w_lin, h), quad-reduce; coalesced per-path store
    float4 wl0 = *(const float4*)(w_lin + quad * 4);
    float4 wl1 = *(const float4*)(w_lin + 16 + quad * 4);
    float s[2];
#pragma unroll
    for (int nt = 0; nt < 2; ++nt) {
        float t = 0.f;
        t = fmaf(wl0.x, hold[nt][0][0], t); t = fmaf(wl0.y, hold[nt][0][1], t);
        t = fmaf(wl0.z, hold[nt][0][2], t); t = fmaf(wl0.w, hold[nt][0][3], t);
        t = fmaf(wl1.x, hold[nt][1][0], t); t = fmaf(wl1.y, hold[nt][1][1], t);
        t = fmaf(wl1.z, hold[nt][1][2], t); t = fmaf(wl1.w, hold[nt][1][3], t);
        t += __shfl_xor(t, 16, 64);
        t += __shfl_xor(t, 32, 64);
        s[nt] = t;
    }
    if (quad < 2) {
        int p = pbase + quad * 16 + lc;
        float val = (quad ? s[1] : s[0]) + b_lin[0];
        if (STORE) psc[p] = val;
        else       atomicAdd(&score[path_idx[p]], val);
    }
}

// ---------------- segment-sum: 64 blocks, LDS bins, 1 global atomic/bin/block ----------------
__global__ __launch_bounds__(1024) void reduce_kernel(const float* __restrict__ psc,
                                                      const int* __restrict__ path_idx,
                                                      float* __restrict__ out)
{
    __shared__ float bins[REALBZ];
    const int tid = threadIdx.x;
    bins[tid] = 0.f;
    __syncthreads();
    const int4*   pi4 = (const int4*)path_idx;
    const float4* ps4 = (const float4*)psc;
#pragma unroll 1
    for (int i = blockIdx.x * 1024 + tid; i < N_PATHS / 4; i += RED_BLOCKS * 1024) {
        int4   idx = pi4[i];
        float4 v   = ps4[i];
        atomicAdd(&bins[idx.x], v.x);
        atomicAdd(&bins[idx.y], v.y);
        atomicAdd(&bins[idx.z], v.z);
        atomicAdd(&bins[idx.w], v.w);
    }
    __syncthreads();
    atomicAdd(&out[tid], bins[tid]);
}

extern "C" void kernel_launch(void* const* d_in, const int* in_sizes, int n_in,
                              void* d_out, int out_size, void* d_ws, size_t ws_size,
                              hipStream_t stream)
{
    // 0 users 1 path 2 path_idx 3 all_emb 4 edge_emb 5 virtual_emb(unused)
    // 6 w_ih 7 w_hh 8 b_ih 9 b_hh 10 w_lin 11 b_lin
    const int*   path     = (const int*)  d_in[1];
    const int*   path_idx = (const int*)  d_in[2];
    const float* all_emb  = (const float*)d_in[3];
    const float* edge_emb = (const float*)d_in[4];
    const float* w_ih     = (const float*)d_in[6];
    const float* w_hh     = (const float*)d_in[7];
    const float* b_ih     = (const float*)d_in[8];
    const float* b_hh     = (const float*)d_in[9];
    const float* w_lin    = (const float*)d_in[10];
    const float* b_lin    = (const float*)d_in[11];

    // ws (bytes): embt @0 (8K) | Wihb @8192 (6K) | Whhb @14336 (6K)
    //             | h2b @20480 (256K) | pk @282624 (1.2M) | psc @1482624 (1.2M)
    char* ws = (char*)d_ws;
    unsigned short* embt = (unsigned short*)ws;
    unsigned short* Wihb = (unsigned short*)(ws + 8192);
    unsigned short* Whhb = (unsigned short*)(ws + 14336);
    unsigned short* h2b  = (unsigned short*)(ws + 20480);
    unsigned*       pk   = (unsigned*)(ws + 282624);
    float*          psc  = (float*)(ws + 1482624);
    const size_t need_pk  = 282624 + (size_t)N_PATHS * 4;
    const size_t need_psc = 1482624 + (size_t)N_PATHS * 4;
    const int use_pk  = (ws_size >= need_pk) ? 1 : 0;
    const int use_psc = (ws_size >= need_psc) ? 1 : 0;

    float* score = (float*)d_out;

    const int pack_blocks = use_pk ? (N_PATHS + 255) / 256 : 0;
    prep_kernel<<<556 + pack_blocks, 256, 0, stream>>>(
        path, all_emb, edge_emb, w_ih, w_hh, b_ih, b_hh,
        embt, Wihb, Whhb, h2b, pk, score, use_pk);

    if (use_pk && use_psc) {
        gru_mfma_kernel<1, 1><<<MAIN_GRID, 256, 0, stream>>>(
            path, pk, path_idx, embt, Wihb, Whhb, h2b, b_ih, b_hh, w_lin, b_lin, psc, score);
        reduce_kernel<<<RED_BLOCKS, 1024, 0, stream>>>(psc, path_idx, score);
    } else if (use_pk) {
        gru_mfma_kernel<1, 0><<<MAIN_GRID, 256, 0, stream>>>(
            path, pk, path_idx, embt, Wihb, Whhb, h2b, b_ih, b_hh, w_lin, b_lin, psc, score);
    } else {
        gru_mfma_kernel<0, 0><<<MAIN_GRID, 256, 0, stream>>>(
            path, pk, path_idx, embt, Wihb, Whhb, h2b, b_ih, b_hh, w_lin, b_lin, psc, score);
    }
}